// Round 11
// baseline (396.193 us; speedup 1.0000x reference)
//
#include <hip/hip_runtime.h>
#include <hip/hip_cooperative_groups.h>

namespace cg = cooperative_groups;

using bf16x8 = __attribute__((ext_vector_type(8))) short;
using f32x4  = __attribute__((ext_vector_type(4))) float;
typedef unsigned short u16;
typedef __attribute__((ext_vector_type(8))) unsigned short u16x8;

__device__ __forceinline__ u16 f2b(float f){
  unsigned int i=__float_as_uint(f);
  return (u16)((i + 0x7FFFu + ((i>>16)&1u))>>16);
}
__device__ __forceinline__ void async16(const void* g, void* l){
  __builtin_amdgcn_global_load_lds((__attribute__((address_space(1))) void*)(g),
                                   (__attribute__((address_space(3))) void*)(l), 16, 0, 0);
}
__device__ __forceinline__ float gelu_tanh(float v){
  float u = v*(0.7978845608f + 0.0356774081f*v*v);
  float e = __expf(-2.0f*fabsf(u));
  float th = (1.0f-e)/(1.0f+e);
  th = (u<0.f)? -th : th;
  return 0.5f*v*(1.0f+th);
}

// ---------- prep: weights -> bf16 LDS-image order; zero vb3 planar pad ----------
__global__ void prep_kernel(const float* __restrict__ wqkv, const float* __restrict__ wproj,
                            const float* __restrict__ wfc1, const float* __restrict__ wfc2,
                            u16* __restrict__ tqkv, u16* __restrict__ tproj,
                            u16* __restrict__ tfc1, u16* __restrict__ tfc2,
                            u16* __restrict__ vb3)
{
  int idx = blockIdx.x*256 + threadIdx.x;
  if (idx < 49152){
    int nc = idx>>14, r = idx&16383, i = r>>3, e = r&7, n = i&127, c = i>>7;
    tqkv[idx] = f2b(wqkv[(c*8+e)*384 + nc*128 + n]);
  } else if (idx < 65536){
    int r = idx-49152; int i=r>>3, e=r&7, n=i&127, c=i>>7;
    tproj[r] = f2b(wproj[(c*8+e)*128 + n]);
  } else if (idx < 131072){
    int t = idx-65536; int nc=t>>14, r=t&16383, i=r>>3, e=r&7, n=i&127, c=i>>7;
    tfc1[t] = f2b(wfc1[(c*8+e)*512 + nc*128 + n]);
  } else if (idx < 196608){
    int t = idx-131072; int nc=t>>14, r=t&16383, i=r>>3, e=r&7, n=i&127, c=i>>7;
    tfc2[t] = f2b(wfc2[(nc*128 + c*8 + e)*128 + n]);
  } else {
    int zi = idx - 196608;            // < 262144 : zero the 4 MB planar V
    u16x8 z = {0,0,0,0,0,0,0,0};
    ((u16x8*)vb3)[zi] = z;
  }
}

struct Params {
  const float* x; const float* ln1w; const float* ln1b;
  const u16* tqkv; const float* bqkv; const float* rpb;
  const u16* tproj; const float* bproj; const float* ln2w; const float* ln2b;
  const u16* tfc1; const float* bfc1; const u16* tfc2; const float* bfc2;
  u16* qb; u16* kb; u16* vb3; u16* aout; float* out;
};

#define KT_S 40
#define VT_S 232
#define P_S  152

// ================= PHASE 1: LN1 + QKV, one 32-token x chunk tile =================
__device__ __forceinline__ void phase1_tile(const Params& p, int t, char* smem,
                                            int tid, int wid, int quad, int lrow)
{
  char* lA = smem;            // 32x128 bf16 c-major chunks (8 KB)
  char* lB = smem + 8192;     // 128x128 bf16 chunk image (32 KB)
  const int wm = (wid&1)*16, wn = (wid>>1)*64;
  const int nc = t / 392;
  const int m0 = (t - nc*392) * 32;
  __syncthreads();            // protect LDS reuse across calls

  #pragma unroll
  for (int kk=0;kk<8;kk++){
    int i = tid + kk*256;
    async16(p.tqkv + (size_t)nc*16384 + i*8, lB + i*16);
  }

  {
    const int row = tid>>3, g = tid&7;
    float xv[16];
    const float4* xr = (const float4*)(p.x + (size_t)(m0+row)*128 + g*16);
    float s=0.f, sq=0.f;
    #pragma unroll
    for (int c4=0;c4<4;c4++){
      float4 tt = xr[c4];
      xv[c4*4]=tt.x; xv[c4*4+1]=tt.y; xv[c4*4+2]=tt.z; xv[c4*4+3]=tt.w;
      s += tt.x+tt.y+tt.z+tt.w;
      sq += tt.x*tt.x+tt.y*tt.y+tt.z*tt.z+tt.w*tt.w;
    }
    s  += __shfl_xor(s,1);  s  += __shfl_xor(s,2);  s  += __shfl_xor(s,4);
    sq += __shfl_xor(sq,1); sq += __shfl_xor(sq,2); sq += __shfl_xor(sq,4);
    float mean = s*0.0078125f;
    float rstd = rsqrtf(sq*0.0078125f - mean*mean + 1e-5f);
    const float4* wr = (const float4*)(p.ln1w + g*16);
    const float4* br = (const float4*)(p.ln1b + g*16);
    u16 nv[16];
    #pragma unroll
    for (int c4=0;c4<4;c4++){
      float4 w4 = wr[c4], b4 = br[c4];
      nv[c4*4]   = f2b((xv[c4*4]  -mean)*rstd*w4.x + b4.x);
      nv[c4*4+1] = f2b((xv[c4*4+1]-mean)*rstd*w4.y + b4.y);
      nv[c4*4+2] = f2b((xv[c4*4+2]-mean)*rstd*w4.z + b4.z);
      nv[c4*4+3] = f2b((xv[c4*4+3]-mean)*rstd*w4.w + b4.w);
    }
    #pragma unroll
    for (int cc=0;cc<2;cc++){
      u16x8 pk;
      #pragma unroll
      for (int e=0;e<8;e++) pk[e] = nv[cc*8+e];
      *(u16x8*)(lA + (((g*2+cc)*32 + row)<<4)) = pk;
    }
  }
  __syncthreads();

  f32x4 acc[4] = {};
  #pragma unroll
  for (int ks=0;ks<4;ks++){
    bf16x8 af = ((const bf16x8*)lA)[(ks*4+quad)*32 + wm + lrow];
    #pragma unroll
    for (int j=0;j<4;j++){
      bf16x8 bfr = ((const bf16x8*)lB)[(ks*4+quad)*128 + wn + j*16 + lrow];
      acc[j] = __builtin_amdgcn_mfma_f32_16x16x32_bf16(af, bfr, acc[j], 0,0,0);
    }
  }

  const float scale = 0.17677669529663687f;
  if (nc < 2){
    u16* dst = (nc==0)? p.qb : p.kb;
    #pragma unroll
    for (int j=0;j<4;j++){
      int col = wn + j*16 + lrow;
      float bia = p.bqkv[nc*128 + col];
      #pragma unroll
      for (int r=0;r<4;r++){
        int row = m0 + wm + quad*4 + r;
        float val = acc[j][r] + bia;
        if (nc==0) val *= scale;
        dst[(size_t)row*128 + col] = f2b(val);
      }
    }
  } else {
    int row0 = m0 + wm + quad*4;
    int bq = row0/3136, rem = row0 - bq*3136;
    int yy = rem/56, xx = rem - yy*56;
    float bia[4];
    #pragma unroll
    for (int j=0;j<4;j++) bia[j] = p.bqkv[256 + wn + j*16 + lrow];
    #pragma unroll
    for (int r=0;r<4;r++){
      size_t pbase = (size_t)(yy+3)*64 + (xx+3);
      #pragma unroll
      for (int j=0;j<4;j++){
        int col = wn + j*16 + lrow;
        int hh = col>>5, ch = col&31;
        p.vb3[((size_t)(((bq<<2)+hh)*32 + ch)<<12) + pbase] = f2b(acc[j][r] + bia[j]);
      }
      xx++;
      if (xx==56){ xx=0; yy++; if (yy==56){ yy=0; bq++; } }
    }
  }
}

// ================= PHASE 2: attention, one (tile, b, h) =================
__device__ __forceinline__ void phase2_tile(const Params& p, int t, char* smem,
                                            int tid, int wid, int quad, int lrow)
{
  u16*  kt   = (u16*)smem;                 // [224][KT_S]
  u16*  vt   = (u16*)(smem + 17920);       // [32][VT_S]
  u16*  Pm   = (u16*)(smem + 32768);       // 4 waves x [16][P_S]
  float* srpb= (float*)(smem + 52224);     // 49 floats
  const int bh = t / 49, tile = t - bh*49;
  const int b = bh>>2, h = bh&3;
  const int ty = (tile/7)*8, tx = (tile%7)*8;
  __syncthreads();

  #pragma unroll
  for (int kk=0;kk<4;kk++){
    int i = tid + kk*256;
    if (i < 896){
      int pos16 = i>>2, oct = i&3;
      int hx = pos16&15, hy = pos16>>4;
      if (hx < 14){
        int gy = ty+hy-3, gx = tx+hx-3;
        u16x8 kv = {0,0,0,0,0,0,0,0};
        if ((unsigned)gy<56u && (unsigned)gx<56u)
          kv = *(const u16x8*)(p.kb + ((size_t)(b*3136 + gy*56 + gx)*128 + h*32 + oct*8));
        *(u16x8*)(kt + pos16*KT_S + oct*8) = kv;
      }
    }
  }
  #pragma unroll
  for (int kk=0;kk<4;kk++){
    int i = tid + kk*256;
    if (i < 896){
      int lo = i&1, t2 = i>>1;
      int ch = t2/14, hy = t2 - ch*14;
      *(u16x8*)(vt + ch*VT_S + hy*16 + lo*8) =
        *(const u16x8*)(p.vb3 + ((size_t)(bh*32 + ch)<<12) + (ty+hy)*64 + tx + lo*8);
    }
  }
  if (tid < 49) srpb[tid] = p.rpb[h*49 + tid];
  __syncthreads();

  const int pxq = wid*16 + lrow;
  const int tokq = b*3136 + (ty + (pxq>>3))*56 + tx + (pxq&7);
  bf16x8 qf = *(const bf16x8*)(p.qb + (size_t)tokq*128 + h*32 + quad*8);

  f32x4 sc[8];
  const f32x4 zf = {0.f,0.f,0.f,0.f};
  #pragma unroll
  for (int cg=0;cg<8;cg++){
    bf16x8 kf = *(const bf16x8*)(kt + (wid*32 + cg*16 + lrow)*KT_S + quad*8);
    sc[cg] = __builtin_amdgcn_mfma_f32_16x16x32_bf16(qf, kf, zf, 0,0,0);
  }

  const int lyq = quad>>1;
  #pragma unroll
  for (int cg=0;cg<8;cg++){
    int dy = cg - lyq;
    bool rowok = ((unsigned)dy < 7u) && (lrow < 14);
    #pragma unroll
    for (int r=0;r<4;r++){
      int lx = (quad*4+r)&7;
      int dx = lrow - lx;
      bool in = rowok && ((unsigned)dx < 7u);
      float bias = srpb[in ? (dy*7+dx) : 0];
      sc[cg][r] = in ? (sc[cg][r] + bias) : -1e30f;
    }
  }
  float inv[4];
  #pragma unroll
  for (int r=0;r<4;r++){
    float m = sc[0][r];
    #pragma unroll
    for (int cg=1;cg<8;cg++) m = fmaxf(m, sc[cg][r]);
    m = fmaxf(m, __shfl_xor(m,1)); m = fmaxf(m, __shfl_xor(m,2));
    m = fmaxf(m, __shfl_xor(m,4)); m = fmaxf(m, __shfl_xor(m,8));
    float l = 0.f;
    #pragma unroll
    for (int cg=0;cg<8;cg++){ float pp = __expf(sc[cg][r]-m); sc[cg][r]=pp; l+=pp; }
    l += __shfl_xor(l,1); l += __shfl_xor(l,2);
    l += __shfl_xor(l,4); l += __shfl_xor(l,8);
    inv[r]=1.f/l;
  }

  u16* Pw = Pm + wid*16*P_S;
  #pragma unroll
  for (int cg=0;cg<8;cg++){
    #pragma unroll
    for (int r=0;r<4;r++)
      Pw[(quad*4+r)*P_S + cg*16 + lrow] = f2b(sc[cg][r]);
  }

  f32x4 oacc[2] = {zf, zf};
  #pragma unroll
  for (int ks=0;ks<4;ks++){
    bf16x8 pf = *(const bf16x8*)(Pw + lrow*P_S + ks*32 + quad*8);
    #pragma unroll
    for (int cg2=0;cg2<2;cg2++){
      bf16x8 vf = *(const bf16x8*)(vt + (cg2*16+lrow)*VT_S + wid*32 + ks*32 + quad*8);
      oacc[cg2] = __builtin_amdgcn_mfma_f32_16x16x32_bf16(pf, vf, oacc[cg2], 0,0,0);
    }
  }
  #pragma unroll
  for (int r=0;r<4;r++){
    int px = wid*16 + quad*4 + r;
    int tok = b*3136 + (ty + (px>>3))*56 + tx + (px&7);
    #pragma unroll
    for (int cg2=0;cg2<2;cg2++){
      int ch = h*32 + cg2*16 + lrow;
      p.aout[(size_t)((tok>>5)*16 + (ch>>3))*256 + (tok&31)*8 + (ch&7)]
        = f2b(oacc[cg2][r]*inv[r]);
    }
  }
}

// ================= PHASE 3: proj+LN2+MLP, one 32-token tile =================
__device__ __forceinline__ void phase3_tile(const Params& p, int t, char* smem,
                                            int tid, int wid, int quad, int lrow)
{
  char* lA  = smem;
  char* lB  = smem + 8192;
  char* xn2 = smem + 40960;
  float* redS = (float*)(smem + 49152);
  float* redQ = redS + 64;
  const int wm = (wid&1)*16, wn = (wid>>1)*64;
  const int half = wid>>1;
  const int m0 = t*32;
  __syncthreads();

  #pragma unroll
  for (int kk=0;kk<2;kk++){
    int i = tid + kk*256;
    async16(p.aout + (size_t)t*4096 + i*8, lA + i*16);
  }
  #pragma unroll
  for (int kk=0;kk<8;kk++){
    int i = tid + kk*256;
    async16(p.tproj + (size_t)i*8, lB + i*16);
  }
  __syncthreads();

  f32x4 acc[4] = {};
  #pragma unroll
  for (int ks=0;ks<4;ks++){
    bf16x8 af = ((const bf16x8*)lA)[(ks*4+quad)*32 + wm + lrow];
    #pragma unroll
    for (int j=0;j<4;j++){
      bf16x8 bfr = ((const bf16x8*)lB)[(ks*4+quad)*128 + wn + j*16 + lrow];
      acc[j] = __builtin_amdgcn_mfma_f32_16x16x32_bf16(af, bfr, acc[j], 0,0,0);
    }
  }

  float x1v[4][4];
  float ps[4] = {}, pq[4] = {};
  #pragma unroll
  for (int j=0;j<4;j++){
    int col = wn + j*16 + lrow;
    float bia = p.bproj[col];
    #pragma unroll
    for (int r=0;r<4;r++){
      int row = m0 + wm + quad*4 + r;
      float val = acc[j][r] + bia + p.x[(size_t)row*128 + col];
      x1v[j][r] = val;
      ps[r] += val; pq[r] += val*val;
    }
  }
  #pragma unroll
  for (int r=0;r<4;r++){
    #pragma unroll
    for (int off=1; off<16; off<<=1){
      ps[r] += __shfl_xor(ps[r], off);
      pq[r] += __shfl_xor(pq[r], off);
    }
  }
  if (lrow==0){
    #pragma unroll
    for (int r=0;r<4;r++){
      int row = wm + quad*4 + r;
      redS[half*32 + row] = ps[r];
      redQ[half*32 + row] = pq[r];
    }
  }
  __syncthreads();

  {
    float w2[4], b2[4];
    #pragma unroll
    for (int j=0;j<4;j++){ int col = wn+j*16+lrow; w2[j]=p.ln2w[col]; b2[j]=p.ln2b[col]; }
    #pragma unroll
    for (int r=0;r<4;r++){
      int row = wm + quad*4 + r;
      float mean = (redS[row] + redS[32+row])*0.0078125f;
      float var  = (redQ[row] + redQ[32+row])*0.0078125f - mean*mean;
      float rstd = rsqrtf(var + 1e-5f);
      #pragma unroll
      for (int j=0;j<4;j++){
        int col = wn + j*16 + lrow;
        u16 hv = f2b((x1v[j][r]-mean)*rstd*w2[j] + b2[j]);
        ((u16*)xn2)[((col>>3)*32 + row)*8 + (col&7)] = hv;
      }
    }
  }
  __syncthreads();

  f32x4 acc3[4] = {};
  for (int nc=0; nc<4; nc++){
    if (nc>0) __syncthreads();
    #pragma unroll
    for (int kk=0;kk<8;kk++){
      int i = tid + kk*256;
      async16(p.tfc1 + (size_t)nc*16384 + i*8, lB + i*16);
    }
    __syncthreads();

    f32x4 acc2[4] = {};
    #pragma unroll
    for (int ks=0;ks<4;ks++){
      bf16x8 af = ((const bf16x8*)xn2)[(ks*4+quad)*32 + wm + lrow];
      #pragma unroll
      for (int j=0;j<4;j++){
        bf16x8 bfr = ((const bf16x8*)lB)[(ks*4+quad)*128 + wn + j*16 + lrow];
        acc2[j] = __builtin_amdgcn_mfma_f32_16x16x32_bf16(af, bfr, acc2[j], 0,0,0);
      }
    }
    #pragma unroll
    for (int j=0;j<4;j++){
      int col = wn + j*16 + lrow;
      float bia = p.bfc1[nc*128 + col];
      #pragma unroll
      for (int r=0;r<4;r++){
        int row = wm + quad*4 + r;
        float g = gelu_tanh(acc2[j][r] + bia);
        ((u16*)lA)[((col>>3)*32 + row)*8 + (col&7)] = f2b(g);
      }
    }
    __syncthreads();
    #pragma unroll
    for (int kk=0;kk<8;kk++){
      int i = tid + kk*256;
      async16(p.tfc2 + (size_t)nc*16384 + i*8, lB + i*16);
    }
    __syncthreads();

    #pragma unroll
    for (int ks=0;ks<4;ks++){
      bf16x8 af = ((const bf16x8*)lA)[(ks*4+quad)*32 + wm + lrow];
      #pragma unroll
      for (int j=0;j<4;j++){
        bf16x8 bfr = ((const bf16x8*)lB)[(ks*4+quad)*128 + wn + j*16 + lrow];
        acc3[j] = __builtin_amdgcn_mfma_f32_16x16x32_bf16(af, bfr, acc3[j], 0,0,0);
      }
    }
  }

  #pragma unroll
  for (int j=0;j<4;j++){
    int col = wn + j*16 + lrow;
    float bia = p.bfc2[col];
    #pragma unroll
    for (int r=0;r<4;r++){
      int row = m0 + wm + quad*4 + r;
      p.out[(size_t)row*128 + col] = acc3[j][r] + bia + x1v[j][r];
    }
  }
}

// ---------- standalone wrappers (fallback path) ----------
__global__ __launch_bounds__(256) void qkv_kernel(Params p){
  __shared__ __align__(16) char smem[40960];
  int tid=threadIdx.x, lane=tid&63, wid=tid>>6, quad=lane>>4, lrow=lane&15;
  phase1_tile(p, blockIdx.x, smem, tid, wid, quad, lrow);
}
__global__ __launch_bounds__(256) void attn_kernel(Params p){
  __shared__ __align__(16) char smem[52480];
  int tid=threadIdx.x, lane=tid&63, wid=tid>>6, quad=lane>>4, lrow=lane&15;
  phase2_tile(p, blockIdx.x, smem, tid, wid, quad, lrow);
}
__global__ __launch_bounds__(256) void mega_kernel(Params p){
  __shared__ __align__(16) char smem[49664];
  int tid=threadIdx.x, lane=tid&63, wid=tid>>6, quad=lane>>4, lrow=lane&15;
  phase3_tile(p, blockIdx.x, smem, tid, wid, quad, lrow);
}

// ---------- fused cooperative kernel ----------
__global__ __launch_bounds__(256) void fused_kernel(Params p){
  __shared__ __align__(16) char smem[52480];
  cg::grid_group grid = cg::this_grid();
  int tid=threadIdx.x, lane=tid&63, wid=tid>>6, quad=lane>>4, lrow=lane&15;
  int gs = gridDim.x;

  for (int t = blockIdx.x; t < 1176; t += gs)
    phase1_tile(p, t, smem, tid, wid, quad, lrow);
  __threadfence();
  grid.sync();
  for (int t = blockIdx.x; t < 784; t += gs)
    phase2_tile(p, t, smem, tid, wid, quad, lrow);
  __threadfence();
  grid.sync();
  for (int t = blockIdx.x; t < 392; t += gs)
    phase3_tile(p, t, smem, tid, wid, quad, lrow);
}

extern "C" void kernel_launch(void* const* d_in, const int* in_sizes, int n_in,
                              void* d_out, int out_size, void* d_ws, size_t ws_size,
                              hipStream_t stream)
{
  const float* x     =(const float*)d_in[0];
  const float* ln1w  =(const float*)d_in[1];
  const float* ln1b  =(const float*)d_in[2];
  const float* wqkv  =(const float*)d_in[3];
  const float* bqkv  =(const float*)d_in[4];
  const float* rpb   =(const float*)d_in[5];
  const float* wproj =(const float*)d_in[6];
  const float* bproj =(const float*)d_in[7];
  const float* ln2w  =(const float*)d_in[8];
  const float* ln2b  =(const float*)d_in[9];
  const float* wfc1  =(const float*)d_in[10];
  const float* bfc1  =(const float*)d_in[11];
  const float* wfc2  =(const float*)d_in[12];
  const float* bfc2  =(const float*)d_in[13];

  char* ws=(char*)d_ws;
  size_t o=0;
  u16* tqkv =(u16*)(ws+o); o+=98304;
  u16* tproj=(u16*)(ws+o); o+=32768;
  u16* tfc1 =(u16*)(ws+o); o+=131072;
  u16* tfc2 =(u16*)(ws+o); o+=131072;
  u16* aout =(u16*)(ws+o); o+=3211264;
  u16* qb   =(u16*)(ws+o); o+=3211264;
  u16* kb   =(u16*)(ws+o); o+=3211264;
  u16* vb3  =(u16*)(ws+o); o+=4194304;   // planar padded V [16][32][64*64]

  prep_kernel<<<1792,256,0,stream>>>(wqkv,wproj,wfc1,wfc2,tqkv,tproj,tfc1,tfc2,vb3);

  Params prm;
  prm.x=x; prm.ln1w=ln1w; prm.ln1b=ln1b;
  prm.tqkv=tqkv; prm.bqkv=bqkv; prm.rpb=rpb;
  prm.tproj=tproj; prm.bproj=bproj; prm.ln2w=ln2w; prm.ln2b=ln2b;
  prm.tfc1=tfc1; prm.bfc1=bfc1; prm.tfc2=tfc2; prm.bfc2=bfc2;
  prm.qb=qb; prm.kb=kb; prm.vb3=vb3; prm.aout=aout; prm.out=(float*)d_out;

  void* args[] = { &prm };
  hipError_t e = hipLaunchCooperativeKernel((const void*)fused_kernel, dim3(512),
                                            dim3(256), args, 0, stream);
  if (e != hipSuccess){
    e = hipLaunchCooperativeKernel((const void*)fused_kernel, dim3(256),
                                   dim3(256), args, 0, stream);
  }
  if (e != hipSuccess){
    qkv_kernel <<<1176,256,0,stream>>>(prm);
    attn_kernel<<< 784,256,0,stream>>>(prm);
    mega_kernel<<< 392,256,0,stream>>>(prm);
  }
}

// Round 12
// 130.957 us; speedup vs baseline: 3.0254x; 3.0254x over previous
//
#include <hip/hip_runtime.h>

using bf16x8 = __attribute__((ext_vector_type(8))) short;
using f32x4  = __attribute__((ext_vector_type(4))) float;
typedef unsigned short u16;
typedef __attribute__((ext_vector_type(8))) unsigned short u16x8;

__device__ __forceinline__ u16 f2b(float f){
  unsigned int i=__float_as_uint(f);
  return (u16)((i + 0x7FFFu + ((i>>16)&1u))>>16);
}
__device__ __forceinline__ void async16(const void* g, void* l){
  __builtin_amdgcn_global_load_lds((__attribute__((address_space(1))) void*)(g),
                                   (__attribute__((address_space(3))) void*)(l), 16, 0, 0);
}
__device__ __forceinline__ float gelu_tanh(float v){
  float u = v*(0.7978845608f + 0.0356774081f*v*v);
  float e = __expf(-2.0f*fabsf(u));
  float th = (1.0f-e)/(1.0f+e);
  th = (u<0.f)? -th : th;
  return 0.5f*v*(1.0f+th);
}

// ---------- prep: weights -> bf16 LDS-image order; zero vb3 planar pad ----------
__global__ void prep_kernel(const float* __restrict__ wqkv, const float* __restrict__ wproj,
                            const float* __restrict__ wfc1, const float* __restrict__ wfc2,
                            u16* __restrict__ tqkv, u16* __restrict__ tproj,
                            u16* __restrict__ tfc1, u16* __restrict__ tfc2,
                            u16* __restrict__ vb3)
{
  int idx = blockIdx.x*256 + threadIdx.x;
  if (idx < 49152){
    int nc = idx>>14, r = idx&16383, i = r>>3, e = r&7, n = i&127, c = i>>7;
    tqkv[idx] = f2b(wqkv[(c*8+e)*384 + nc*128 + n]);
  } else if (idx < 65536){
    int r = idx-49152; int i=r>>3, e=r&7, n=i&127, c=i>>7;
    tproj[r] = f2b(wproj[(c*8+e)*128 + n]);
  } else if (idx < 131072){
    int t = idx-65536; int nc=t>>14, r=t&16383, i=r>>3, e=r&7, n=i&127, c=i>>7;
    tfc1[t] = f2b(wfc1[(c*8+e)*512 + nc*128 + n]);
  } else if (idx < 196608){
    int t = idx-131072; int nc=t>>14, r=t&16383, i=r>>3, e=r&7, n=i&127, c=i>>7;
    tfc2[t] = f2b(wfc2[(nc*128 + c*8 + e)*128 + n]);
  } else {
    int zi = idx - 196608;            // < 262144 : zero the 4 MB planar V
    u16x8 z = {0,0,0,0,0,0,0,0};
    ((u16x8*)vb3)[zi] = z;
  }
}

// aout layout: per 32-token group, c-major chunks:
//   u16 index = ((tok>>5)*16 + (ch>>3))*256 + (tok&31)*8 + (ch&7)
// vb3 layout: planar padded: [(b*4+h)*32+ch][ (y+3)*64 + (x+3) ]

// ---------- K2: LN1 + one QKV chunk GEMM. 32-token tile, grid (392,3), LDS 40KB ----------
__global__ __launch_bounds__(256)
void qkv_kernel(const float* __restrict__ x,
                const float* __restrict__ ln1w, const float* __restrict__ ln1b,
                const u16* __restrict__ tqkv, const float* __restrict__ bqkv,
                u16* __restrict__ qb, u16* __restrict__ kb, u16* __restrict__ vb3)
{
  __shared__ __align__(16) char smem[40960];
  char* lA = smem;            // 32x128 bf16 c-major chunks (8 KB)
  char* lB = smem + 8192;     // 128x128 bf16 chunk image (32 KB)

  const int tid = threadIdx.x;
  const int lane = tid&63, wid = tid>>6;
  const int quad = lane>>4, lrow = lane&15;
  const int m0 = blockIdx.x*32;
  const int nc = blockIdx.y;
  const int wm = (wid&1)*16, wn = (wid>>1)*64;

  #pragma unroll
  for (int kk=0;kk<8;kk++){
    int i = tid + kk*256;
    async16(tqkv + (size_t)nc*16384 + i*8, lB + i*16);
  }

  {
    const int row = tid>>3, g = tid&7;
    float xv[16];
    const float4* xr = (const float4*)(x + (size_t)(m0+row)*128 + g*16);
    float s=0.f, sq=0.f;
    #pragma unroll
    for (int c4=0;c4<4;c4++){
      float4 tt = xr[c4];
      xv[c4*4]=tt.x; xv[c4*4+1]=tt.y; xv[c4*4+2]=tt.z; xv[c4*4+3]=tt.w;
      s += tt.x+tt.y+tt.z+tt.w;
      sq += tt.x*tt.x+tt.y*tt.y+tt.z*tt.z+tt.w*tt.w;
    }
    s  += __shfl_xor(s,1);  s  += __shfl_xor(s,2);  s  += __shfl_xor(s,4);
    sq += __shfl_xor(sq,1); sq += __shfl_xor(sq,2); sq += __shfl_xor(sq,4);
    float mean = s*0.0078125f;
    float rstd = rsqrtf(sq*0.0078125f - mean*mean + 1e-5f);
    const float4* wr = (const float4*)(ln1w + g*16);
    const float4* br = (const float4*)(ln1b + g*16);
    u16 nv[16];
    #pragma unroll
    for (int c4=0;c4<4;c4++){
      float4 w4 = wr[c4], b4 = br[c4];
      nv[c4*4]   = f2b((xv[c4*4]  -mean)*rstd*w4.x + b4.x);
      nv[c4*4+1] = f2b((xv[c4*4+1]-mean)*rstd*w4.y + b4.y);
      nv[c4*4+2] = f2b((xv[c4*4+2]-mean)*rstd*w4.z + b4.z);
      nv[c4*4+3] = f2b((xv[c4*4+3]-mean)*rstd*w4.w + b4.w);
    }
    #pragma unroll
    for (int cc=0;cc<2;cc++){
      u16x8 pk;
      #pragma unroll
      for (int e=0;e<8;e++) pk[e] = nv[cc*8+e];
      *(u16x8*)(lA + (((g*2+cc)*32 + row)<<4)) = pk;
    }
  }
  __syncthreads();

  f32x4 acc[4] = {};
  #pragma unroll
  for (int ks=0;ks<4;ks++){
    bf16x8 af = ((const bf16x8*)lA)[(ks*4+quad)*32 + wm + lrow];
    #pragma unroll
    for (int j=0;j<4;j++){
      bf16x8 bfr = ((const bf16x8*)lB)[(ks*4+quad)*128 + wn + j*16 + lrow];
      acc[j] = __builtin_amdgcn_mfma_f32_16x16x32_bf16(af, bfr, acc[j], 0,0,0);
    }
  }

  const float scale = 0.17677669529663687f;
  if (nc < 2){
    u16* dst = (nc==0)? qb : kb;
    #pragma unroll
    for (int j=0;j<4;j++){
      int col = wn + j*16 + lrow;
      float bia = bqkv[nc*128 + col];
      #pragma unroll
      for (int r=0;r<4;r++){
        int row = m0 + wm + quad*4 + r;
        float val = acc[j][r] + bia;
        if (nc==0) val *= scale;
        dst[(size_t)row*128 + col] = f2b(val);
      }
    }
  } else {
    int row0 = m0 + wm + quad*4;
    int bq = row0/3136, rem = row0 - bq*3136;
    int yy = rem/56, xx = rem - yy*56;
    float bia[4];
    #pragma unroll
    for (int j=0;j<4;j++) bia[j] = bqkv[256 + wn + j*16 + lrow];
    #pragma unroll
    for (int r=0;r<4;r++){
      size_t pbase = (size_t)(yy+3)*64 + (xx+3);
      #pragma unroll
      for (int j=0;j<4;j++){
        int col = wn + j*16 + lrow;
        int hh = col>>5, ch = col&31;
        vb3[((size_t)(((bq<<2)+hh)*32 + ch)<<12) + pbase] = f2b(acc[j][r] + bia[j]);
      }
      xx++;
      if (xx==56){ xx=0; yy++; if (yy==56){ yy=0; bq++; } }
    }
  }
}

// ---------- K3: MFMA neighborhood attention; LDS 33 KB (P overlays dead kt) ----------
#define KT_S 40
#define VT_S 232
#define P_S  136
__global__ __launch_bounds__(256)
void attn_kernel(const u16* __restrict__ qb, const u16* __restrict__ kb,
                 const u16* __restrict__ vb3, const float* __restrict__ rpb,
                 u16* __restrict__ aout)
{
  __shared__ __align__(16) char smem[33024];
  u16*  kt   = (u16*)smem;                 // [224][KT_S] = 17920 B (P overlays later)
  u16*  vt   = (u16*)(smem + 17920);       // [32][VT_S]  = 14848 B
  float* srpb= (float*)(smem + 32768);     // 49 floats

  const int tid = threadIdx.x;
  const int tile = blockIdx.x, bh = blockIdx.y;
  const int b = bh>>2, h = bh&3;
  const int ty = (tile/7)*8, tx = (tile%7)*8;
  const int lane = tid&63, wid = tid>>6;
  const int quad = lane>>4, lrow = lane&15;

  #pragma unroll
  for (int kk=0;kk<4;kk++){
    int i = tid + kk*256;
    if (i < 896){
      int pos16 = i>>2, oct = i&3;
      int hx = pos16&15, hy = pos16>>4;
      if (hx < 14){
        int gy = ty+hy-3, gx = tx+hx-3;
        u16x8 kv = {0,0,0,0,0,0,0,0};
        if ((unsigned)gy<56u && (unsigned)gx<56u)
          kv = *(const u16x8*)(kb + ((size_t)(b*3136 + gy*56 + gx)*128 + h*32 + oct*8));
        *(u16x8*)(kt + pos16*KT_S + oct*8) = kv;
      }
    }
  }
  #pragma unroll
  for (int kk=0;kk<4;kk++){
    int i = tid + kk*256;
    if (i < 896){
      int lo = i&1, t2 = i>>1;
      int ch = t2/14, hy = t2 - ch*14;
      *(u16x8*)(vt + ch*VT_S + hy*16 + lo*8) =
        *(const u16x8*)(vb3 + ((size_t)(bh*32 + ch)<<12) + (ty+hy)*64 + tx + lo*8);
    }
  }
  if (tid < 49) srpb[tid] = rpb[h*49 + tid];
  __syncthreads();

  const int pxq = wid*16 + lrow;
  const int tokq = b*3136 + (ty + (pxq>>3))*56 + tx + (pxq&7);
  bf16x8 qf = *(const bf16x8*)(qb + (size_t)tokq*128 + h*32 + quad*8);

  f32x4 sc[8];
  const f32x4 zf = {0.f,0.f,0.f,0.f};
  #pragma unroll
  for (int cg=0;cg<8;cg++){
    bf16x8 kf = *(const bf16x8*)(kt + (wid*32 + cg*16 + lrow)*KT_S + quad*8);
    sc[cg] = __builtin_amdgcn_mfma_f32_16x16x32_bf16(qf, kf, zf, 0,0,0);
  }

  const int lyq = quad>>1;
  #pragma unroll
  for (int cg=0;cg<8;cg++){
    int dy = cg - lyq;
    bool rowok = ((unsigned)dy < 7u) && (lrow < 14);
    #pragma unroll
    for (int r=0;r<4;r++){
      int lx = (quad*4+r)&7;
      int dx = lrow - lx;
      bool in = rowok && ((unsigned)dx < 7u);
      float bias = srpb[in ? (dy*7+dx) : 0];
      sc[cg][r] = in ? (sc[cg][r] + bias) : -1e30f;
    }
  }
  float inv[4];
  #pragma unroll
  for (int r=0;r<4;r++){
    float m = sc[0][r];
    #pragma unroll
    for (int cg=1;cg<8;cg++) m = fmaxf(m, sc[cg][r]);
    m = fmaxf(m, __shfl_xor(m,1)); m = fmaxf(m, __shfl_xor(m,2));
    m = fmaxf(m, __shfl_xor(m,4)); m = fmaxf(m, __shfl_xor(m,8));
    float l = 0.f;
    #pragma unroll
    for (int cg=0;cg<8;cg++){ float pp = __expf(sc[cg][r]-m); sc[cg][r]=pp; l+=pp; }
    l += __shfl_xor(l,1); l += __shfl_xor(l,2);
    l += __shfl_xor(l,4); l += __shfl_xor(l,8);
    inv[r]=1.f/l;
  }

  __syncthreads();   // all waves done reading kt -> safe to overlay P
  u16* Pw = kt + wid*16*P_S;          // wave-private region, 4x4352 B = 17408 <= 17920
  #pragma unroll
  for (int cg=0;cg<8;cg++){
    #pragma unroll
    for (int r=0;r<4;r++)
      Pw[(quad*4+r)*P_S + cg*16 + lrow] = f2b(sc[cg][r]);
  }

  f32x4 oacc[2] = {zf, zf};
  #pragma unroll
  for (int ks=0;ks<4;ks++){
    bf16x8 pf = *(const bf16x8*)(Pw + lrow*P_S + ks*32 + quad*8);
    #pragma unroll
    for (int cg2=0;cg2<2;cg2++){
      bf16x8 vf = *(const bf16x8*)(vt + (cg2*16+lrow)*VT_S + wid*32 + ks*32 + quad*8);
      oacc[cg2] = __builtin_amdgcn_mfma_f32_16x16x32_bf16(pf, vf, oacc[cg2], 0,0,0);
    }
  }
  #pragma unroll
  for (int r=0;r<4;r++){
    int px = wid*16 + quad*4 + r;
    int tok = b*3136 + (ty + (px>>3))*56 + tx + (px&7);
    #pragma unroll
    for (int cg2=0;cg2<2;cg2++){
      int ch = h*32 + cg2*16 + lrow;
      aout[(size_t)((tok>>5)*16 + (ch>>3))*256 + (tok&31)*8 + (ch&7)]
        = f2b(oacc[cg2][r]*inv[r]);
    }
  }
}

// ---------- K4: PROJ+res+LN2+FC1+GELU+FC2+res. 16-token tile, grid 784, LDS 40KB ----------
__global__ __launch_bounds__(256)
void mega_kernel(const u16* __restrict__ aout, const float* __restrict__ x,
                 const u16* __restrict__ tproj, const float* __restrict__ bproj,
                 const float* __restrict__ ln2w, const float* __restrict__ ln2b,
                 const u16* __restrict__ tfc1, const float* __restrict__ bfc1,
                 const u16* __restrict__ tfc2, const float* __restrict__ bfc2,
                 float* __restrict__ out)
{
  __shared__ __align__(16) char smem[40960];
  char* lA  = smem;            // 4 KB: aout tile -> red overlay -> hid chunk
  char* lB  = smem + 4096;     // 32 KB: weight chunk
  char* xn2 = smem + 36864;    // 4 KB: LN2 out bf16 image

  const int tid = threadIdx.x;
  const int lane = tid&63, wid = tid>>6;
  const int quad = lane>>4, lrow = lane&15;
  const int t = blockIdx.x;               // 0..783
  const int m0 = t*16;
  const int g = t>>1, off = (t&1)*16;     // aout 32-token group / row offset
  const int wn = wid*32;

  // ---- stage aout 16x128 (256 chunks) + proj weights ----
  { int i = tid; int c = i>>4, row = i&15;
    async16(aout + (size_t)(g*16 + c)*256 + (off+row)*8, lA + i*16); }
  #pragma unroll
  for (int kk=0;kk<8;kk++){
    int i = tid + kk*256;
    async16(tproj + (size_t)i*8, lB + i*16);
  }
  __syncthreads();

  // ---- proj MFMA: 16 rows x 128 cols, wave = 32 cols ----
  f32x4 acc[2] = {};
  #pragma unroll
  for (int ks=0;ks<4;ks++){
    bf16x8 af = ((const bf16x8*)lA)[(ks*4+quad)*16 + lrow];
    #pragma unroll
    for (int j=0;j<2;j++){
      bf16x8 bfr = ((const bf16x8*)lB)[(ks*4+quad)*128 + wn + j*16 + lrow];
      acc[j] = __builtin_amdgcn_mfma_f32_16x16x32_bf16(af, bfr, acc[j], 0,0,0);
    }
  }

  // ---- x1 = proj + bias + x; row-stat partials ----
  float x1v[2][4];
  float ps[4] = {}, pq[4] = {};
  #pragma unroll
  for (int j=0;j<2;j++){
    int col = wn + j*16 + lrow;
    float bia = bproj[col];
    #pragma unroll
    for (int r=0;r<4;r++){
      int row = m0 + quad*4 + r;
      float val = acc[j][r] + bia + x[(size_t)row*128 + col];
      x1v[j][r] = val;
      ps[r] += val; pq[r] += val*val;
    }
  }
  #pragma unroll
  for (int r=0;r<4;r++){
    #pragma unroll
    for (int o2=1; o2<16; o2<<=1){
      ps[r] += __shfl_xor(ps[r], o2);
      pq[r] += __shfl_xor(pq[r], o2);
    }
  }
  __syncthreads();                         // lA MFMA reads done -> overlay red
  float* redS = (float*)lA;                // [64]
  float* redQ = redS + 64;                 // [64]
  if (lrow==0){
    #pragma unroll
    for (int r=0;r<4;r++){
      int row = quad*4 + r;
      redS[wid*16 + row] = ps[r];
      redQ[wid*16 + row] = pq[r];
    }
  }
  __syncthreads();

  // ---- LN2 -> xn2 image ----
  {
    float w2[2], b2[2];
    #pragma unroll
    for (int j=0;j<2;j++){ int col = wn+j*16+lrow; w2[j]=ln2w[col]; b2[j]=ln2b[col]; }
    #pragma unroll
    for (int r=0;r<4;r++){
      int row = quad*4 + r;
      float s = redS[row] + redS[16+row] + redS[32+row] + redS[48+row];
      float q = redQ[row] + redQ[16+row] + redQ[32+row] + redQ[48+row];
      float mean = s*0.0078125f;
      float var  = q*0.0078125f - mean*mean;
      float rstd = rsqrtf(var + 1e-5f);
      #pragma unroll
      for (int j=0;j<2;j++){
        int col = wn + j*16 + lrow;
        u16 hv = f2b((x1v[j][r]-mean)*rstd*w2[j] + b2[j]);
        ((u16*)xn2)[((col>>3)*16 + row)*8 + (col&7)] = hv;
      }
    }
  }
  __syncthreads();

  // ---- FC1(chunk) + GELU + FC2(chunk) accumulate ----
  f32x4 acc3[2] = {};
  for (int nc=0; nc<4; nc++){
    if (nc>0) __syncthreads();
    #pragma unroll
    for (int kk=0;kk<8;kk++){
      int i = tid + kk*256;
      async16(tfc1 + (size_t)nc*16384 + i*8, lB + i*16);
    }
    __syncthreads();

    f32x4 acc2[2] = {};
    #pragma unroll
    for (int ks=0;ks<4;ks++){
      bf16x8 af = ((const bf16x8*)xn2)[(ks*4+quad)*16 + lrow];
      #pragma unroll
      for (int j=0;j<2;j++){
        bf16x8 bfr = ((const bf16x8*)lB)[(ks*4+quad)*128 + wn + j*16 + lrow];
        acc2[j] = __builtin_amdgcn_mfma_f32_16x16x32_bf16(af, bfr, acc2[j], 0,0,0);
      }
    }
    #pragma unroll
    for (int j=0;j<2;j++){
      int col = wn + j*16 + lrow;
      float bia = bfc1[nc*128 + col];
      #pragma unroll
      for (int r=0;r<4;r++){
        int row = quad*4 + r;
        float gg = gelu_tanh(acc2[j][r] + bia);
        ((u16*)lA)[((col>>3)*16 + row)*8 + (col&7)] = f2b(gg);
      }
    }
    __syncthreads();
    #pragma unroll
    for (int kk=0;kk<8;kk++){
      int i = tid + kk*256;
      async16(tfc2 + (size_t)nc*16384 + i*8, lB + i*16);
    }
    __syncthreads();

    #pragma unroll
    for (int ks=0;ks<4;ks++){
      bf16x8 af = ((const bf16x8*)lA)[(ks*4+quad)*16 + lrow];
      #pragma unroll
      for (int j=0;j<2;j++){
        bf16x8 bfr = ((const bf16x8*)lB)[(ks*4+quad)*128 + wn + j*16 + lrow];
        acc3[j] = __builtin_amdgcn_mfma_f32_16x16x32_bf16(af, bfr, acc3[j], 0,0,0);
      }
    }
  }

  // ---- epilogue: out = fc2 + bias + x1 ----
  #pragma unroll
  for (int j=0;j<2;j++){
    int col = wn + j*16 + lrow;
    float bia = bfc2[col];
    #pragma unroll
    for (int r=0;r<4;r++){
      int row = m0 + quad*4 + r;
      out[(size_t)row*128 + col] = acc3[j][r] + bia + x1v[j][r];
    }
  }
}

extern "C" void kernel_launch(void* const* d_in, const int* in_sizes, int n_in,
                              void* d_out, int out_size, void* d_ws, size_t ws_size,
                              hipStream_t stream)
{
  const float* x     =(const float*)d_in[0];
  const float* ln1w  =(const float*)d_in[1];
  const float* ln1b  =(const float*)d_in[2];
  const float* wqkv  =(const float*)d_in[3];
  const float* bqkv  =(const float*)d_in[4];
  const float* rpb   =(const float*)d_in[5];
  const float* wproj =(const float*)d_in[6];
  const float* bproj =(const float*)d_in[7];
  const float* ln2w  =(const float*)d_in[8];
  const float* ln2b  =(const float*)d_in[9];
  const float* wfc1  =(const float*)d_in[10];
  const float* bfc1  =(const float*)d_in[11];
  const float* wfc2  =(const float*)d_in[12];
  const float* bfc2  =(const float*)d_in[13];

  char* ws=(char*)d_ws;
  size_t o=0;
  u16* tqkv =(u16*)(ws+o); o+=98304;
  u16* tproj=(u16*)(ws+o); o+=32768;
  u16* tfc1 =(u16*)(ws+o); o+=131072;
  u16* tfc2 =(u16*)(ws+o); o+=131072;
  u16* aout =(u16*)(ws+o); o+=3211264;
  u16* qb   =(u16*)(ws+o); o+=3211264;
  u16* kb   =(u16*)(ws+o); o+=3211264;
  u16* vb3  =(u16*)(ws+o); o+=4194304;   // planar padded V [16][32][64*64]

  prep_kernel<<<1792,256,0,stream>>>(wqkv,wproj,wfc1,wfc2,tqkv,tproj,tfc1,tfc2,vb3);
  qkv_kernel<<<dim3(392,3),256,0,stream>>>(x,ln1w,ln1b,tqkv,bqkv,qb,kb,vb3);
  attn_kernel<<<dim3(49,16),256,0,stream>>>(qb,kb,vb3,rpb,aout);
  mega_kernel<<<784,256,0,stream>>>(aout,x,tproj,bproj,ln2w,ln2b,
                                    tfc1,bfc1,tfc2,bfc2,(float*)d_out);
}